// Round 11
// baseline (350.011 us; speedup 1.0000x reference)
//
#include <hip/hip_runtime.h>
#include <hip/hip_bf16.h>
#include <cstdint>
#include <cstddef>

#define B_ 4
#define L_ 4096
#define D_ 1024
#define FF_ 2048
#define ROWS (B_ * L_)   // 16384
#define EPS_ 1e-5f
#define CG 64            // conv chunks
#define CC 64            // conv chunk length (L_/CG)

typedef __attribute__((ext_vector_type(8))) __bf16 bf16x8;
typedef __attribute__((ext_vector_type(4))) float f32x4;
typedef __attribute__((ext_vector_type(4))) unsigned short us4;

__device__ __forceinline__ float bf2f(unsigned short u) {
  union { unsigned int i; float f; } v; v.i = ((unsigned int)u) << 16; return v.f;
}
__device__ __forceinline__ unsigned short f2bf(float f) {
  union { float f; unsigned int i; } v; v.f = f;
  unsigned int r = v.i + 0x7fffu + ((v.i >> 16) & 1u);
  return (unsigned short)(r >> 16);
}

// ---------------- weight transpose + cast: in [K,N] f32 -> out [N,K] bf16 ----
__global__ __launch_bounds__(256) void transpose_cast(
    const float* __restrict__ in, unsigned short* __restrict__ out, int K, int N) {
  __shared__ float tb[32][33];
  int n0 = blockIdx.x * 32, k0 = blockIdx.y * 32;
  int tx = threadIdx.x & 31, ty = threadIdx.x >> 5;  // 32 x 8
#pragma unroll
  for (int i = 0; i < 4; ++i) {
    int k = ty + i * 8;
    tb[k][tx] = in[(size_t)(k0 + k) * N + n0 + tx];
  }
  __syncthreads();
#pragma unroll
  for (int i = 0; i < 4; ++i) {
    int n = ty + i * 8;
    out[(size_t)(n0 + n) * K + k0 + tx] = f2bf(tb[tx][n]);
  }
}

// ---------------- LN1: x -> xn bf16 (LayerNorm), xb bf16 (plain cast) --------
__global__ __launch_bounds__(256) void ln1_kernel(
    const float* __restrict__ x, const float* __restrict__ g, const float* __restrict__ b,
    unsigned short* __restrict__ xn, unsigned short* __restrict__ xb) {
  int row = blockIdx.x;
  int t = threadIdx.x;
  const float4* xr = (const float4*)(x + (size_t)row * D_);
  float4 v = xr[t];
  float s = v.x + v.y + v.z + v.w;
  float sq = v.x * v.x + v.y * v.y + v.z * v.z + v.w * v.w;
#pragma unroll
  for (int off = 32; off > 0; off >>= 1) {
    s += __shfl_down(s, off);
    sq += __shfl_down(sq, off);
  }
  __shared__ float ls[4], lq[4];
  int lane = t & 63, w = t >> 6;
  if (lane == 0) { ls[w] = s; lq[w] = sq; }
  __syncthreads();
  s = ls[0] + ls[1] + ls[2] + ls[3];
  sq = lq[0] + lq[1] + lq[2] + lq[3];
  float mean = s * (1.0f / D_);
  float var = sq * (1.0f / D_) - mean * mean;
  float rstd = rsqrtf(var + EPS_);
  float4 gv = ((const float4*)g)[t];
  float4 bv = ((const float4*)b)[t];
  us4 o, ob;
  o.x = f2bf((v.x - mean) * rstd * gv.x + bv.x);
  o.y = f2bf((v.y - mean) * rstd * gv.y + bv.y);
  o.z = f2bf((v.z - mean) * rstd * gv.z + bv.z);
  o.w = f2bf((v.w - mean) * rstd * gv.w + bv.w);
  ob.x = f2bf(v.x); ob.y = f2bf(v.y); ob.z = f2bf(v.z); ob.w = f2bf(v.w);
  ((us4*)(xn + (size_t)row * D_))[t] = o;
  ((us4*)(xb + (size_t)row * D_))[t] = ob;
}

// ---------------- conv pass 1: per-chunk local recurrence --------------------
__global__ __launch_bounds__(256) void conv_pass1(
    const unsigned short* __restrict__ xn, const float* __restrict__ ph_re,
    const float* __restrict__ ph_im, float2* __restrict__ rloc) {
  int d = blockIdx.x * 256 + threadIdx.x;
  int g = blockIdx.y, b = blockIdx.z;
  float re = ph_re[d], im = ph_im[d];
  float a = sqrtf(re * re + im * im);
  float sc = expf(-a) / a;
  float pr = re * sc, pi = im * sc;
  float rr = 0.f, ri = 0.f;
  const unsigned short* xp = xn + ((size_t)(b * L_ + g * CC)) * D_ + d;
#pragma unroll 8
  for (int l = 0; l < CC; ++l) {
    float xv = bf2f(xp[(size_t)l * D_]);
    float nr = pr * rr - pi * ri + xv;
    ri = pr * ri + pi * rr;
    rr = nr;
  }
  rloc[((size_t)(b * CG + g)) * D_ + d] = make_float2(rr, ri);
}

// ---------------- conv pass 2: scan over chunks (batch-8 prefetched) ---------
__global__ __launch_bounds__(256) void conv_pass2(
    const float* __restrict__ ph_re, const float* __restrict__ ph_im,
    const float2* __restrict__ rloc, float2* __restrict__ carry) {
  int idx = blockIdx.x * 256 + threadIdx.x;  // 0..B*D-1
  int b = idx >> 10, d = idx & (D_ - 1);
  float re = ph_re[d], im = ph_im[d];
  float a = sqrtf(re * re + im * im);
  float th = atan2f(im, re);
  float rho = expf(-a * (float)CC);
  float ang = th * (float)CC;
  float pcr = rho * cosf(ang), pci = rho * sinf(ang);
  float cr = 0.f, ci = 0.f;
  for (int g0 = 0; g0 < CG; g0 += 8) {
    float2 rl[8];
    float2 cw[8];
#pragma unroll
    for (int i = 0; i < 8; ++i)
      rl[i] = rloc[((size_t)(b * CG + g0 + i)) * D_ + d];
#pragma unroll
    for (int i = 0; i < 8; ++i) {
      cw[i] = make_float2(cr, ci);
      float nr = pcr * cr - pci * ci + rl[i].x;
      ci = pcr * ci + pci * cr + rl[i].y;
      cr = nr;
    }
#pragma unroll
    for (int i = 0; i < 8; ++i)
      carry[((size_t)(b * CG + g0 + i)) * D_ + d] = cw[i];
  }
}

// ---------------- conv pass 3: outputs -------------------------------------
__global__ __launch_bounds__(256) void conv_pass3(
    const unsigned short* __restrict__ xn,
    const float* __restrict__ ph_re, const float* __restrict__ ph_im,
    const float* __restrict__ phi_re, const float* __restrict__ phi_im,
    const float* __restrict__ lci_re, const float* __restrict__ lci_im,
    const float2* __restrict__ carry, unsigned short* __restrict__ cout) {
  int d = blockIdx.x * 256 + threadIdx.x;
  int g = blockIdx.y, b = blockIdx.z;
  float re = ph_re[d], im = ph_im[d];
  float a = sqrtf(re * re + im * im);
  float sc = expf(-a) / a;
  float pr = re * sc, pi = im * sc;
  float th = atan2f(im, re);
  int l0 = g * CC;
  float rho = expf(-a * (float)(l0 + 1));
  float ang = th * (float)(l0 + 1);
  float prr = rho * cosf(ang), pri = rho * sinf(ang);
  float fr = phi_re[d], fi = phi_im[d];
  float qr = lci_re[d], qi = lci_im[d];
  float2 cv = carry[((size_t)(b * CG + g)) * D_ + d];
  float rr = cv.x, ri = cv.y;
  const unsigned short* xp = xn + ((size_t)(b * L_ + l0)) * D_ + d;
  unsigned short* cp = cout + ((size_t)(b * L_ + l0)) * D_ + d;
#pragma unroll 4
  for (int l = 0; l < CC; ++l) {
    float xv = bf2f(xp[(size_t)l * D_]);
    float nr = pr * rr - pi * ri + xv;
    ri = pr * ri + pi * rr;
    rr = nr;
    float outv = fr * rr - fi * ri + qr * prr - qi * pri;  // Re(phi*r + lci*p)
    cp[(size_t)l * D_] = f2bf(outv);
    float pn = pr * prr - pi * pri;
    pri = pr * pri + pi * prr;
    prr = pn;
  }
}

// ---------------- LN2b: x3 = LN(x2 bf16) -> bf16 ----------------------------
__global__ __launch_bounds__(256) void ln2b_kernel(
    const unsigned short* __restrict__ x2, const float* __restrict__ g,
    const float* __restrict__ b, unsigned short* __restrict__ x3) {
  int row = blockIdx.x;
  int t = threadIdx.x;
  size_t base = (size_t)row * D_;
  us4 vb = ((const us4*)(x2 + base))[t];
  float4 v;
  v.x = bf2f(vb.x); v.y = bf2f(vb.y); v.z = bf2f(vb.z); v.w = bf2f(vb.w);
  float s = v.x + v.y + v.z + v.w;
  float sq = v.x * v.x + v.y * v.y + v.z * v.z + v.w * v.w;
#pragma unroll
  for (int off = 32; off > 0; off >>= 1) {
    s += __shfl_down(s, off);
    sq += __shfl_down(sq, off);
  }
  __shared__ float ls[4], lq[4];
  int lane = t & 63, w = t >> 6;
  if (lane == 0) { ls[w] = s; lq[w] = sq; }
  __syncthreads();
  s = ls[0] + ls[1] + ls[2] + ls[3];
  sq = lq[0] + lq[1] + lq[2] + lq[3];
  float mean = s * (1.0f / D_);
  float var = sq * (1.0f / D_) - mean * mean;
  float rstd = rsqrtf(var + EPS_);
  float4 gv = ((const float4*)g)[t];
  float4 bv = ((const float4*)b)[t];
  us4 o;
  o.x = f2bf((v.x - mean) * rstd * gv.x + bv.x);
  o.y = f2bf((v.y - mean) * rstd * gv.y + bv.y);
  o.z = f2bf((v.z - mean) * rstd * gv.z + bv.z);
  o.w = f2bf((v.w - mean) * rstd * gv.w + bv.w);
  ((us4*)(x3 + base))[t] = o;
}

// ============================================================================
// GEMM: A[M,K] bf16 @ Bt[N,K] bf16 -> C [M,N]
// BM=256, BN=128, BK=64. 512 thr = 8 waves (4M x 2N), wave-tile 64x64.
// LDS ring-3 (A 32K + B 16K)x3 = 144 KiB, stage distance 2 (R10 ledger).
// REGISTER PING-PONG, NO FULL DRAINS: fragments for cluster k+1 are issued
// BEFORE cluster k's MFMAs; each cluster waits lgkmcnt(8) (8 newest = the
// just-issued next-cluster reads; all older reads -- this cluster's operands
// -- complete). Read latency (~220cyc) hides under 16-MFMA window (~310cyc).
// Per K-tile: 1 s_barrier, 2x lgkmcnt(8)+sched_barrier (rule-18 fence),
// 1x vmcnt(6) counted (S(T+1) issued a full tile earlier). WAR: reads of
// slot s are lgkm-waited >=1 barrier before s is re-staged (distance-3 ring).
// Swizzle: 16B chunk ^= row&7 both-sides (0-conflict measured R2-R10).
// ============================================================================
__device__ __forceinline__ void gld_lds16(const unsigned short* gp, unsigned short* lp) {
  __builtin_amdgcn_global_load_lds(
      (const __attribute__((address_space(1))) unsigned int*)gp,
      (__attribute__((address_space(3))) unsigned int*)lp, 16, 0, 0);
}

template <int SILU, int RESBF, int OUT_BF16, int GATE>
__global__ __launch_bounds__(512) void gemm_bt(
    const unsigned short* __restrict__ A, const unsigned short* __restrict__ Bt,
    const float* __restrict__ bias, const unsigned short* __restrict__ resb,
    const unsigned short* __restrict__ gate, const unsigned short* __restrict__ xresb,
    void* __restrict__ Cv, int NB, int GROUP, int N, int K) {
  __shared__ unsigned short As[3][256 * 64];  // 3 x 32 KiB
  __shared__ unsigned short Bs[3][128 * 64];  // 3 x 16 KiB

  int nwg = gridDim.x;
  int xcd = blockIdx.x & 7;
  int lo = blockIdx.x >> 3;
  int q = nwg >> 3;               // blocks per XCD
  int gsz = GROUP * NB;
  int g_ = lo / gsz, r_ = lo % gsz;
  int n_ = r_ / GROUP, ml = r_ - n_ * GROUP;
  int Mx = q / NB;                // m-rows per XCD
  int bm0 = (xcd * Mx + g_ * GROUP + ml) * 256;
  int bn0 = n_ * 128;

  int t = threadIdx.x;
  int lane = t & 63, w = t >> 6;
  int wr = w >> 1, wc = w & 1;          // 4M x 2N waves
  int frr = lane & 15, cl = lane >> 4;
  int fx = frr & 7;
  int rA0 = wr * 64 + frr;
  int rB0 = wc * 64 + frr;
  int ko0 = (cl ^ fx) * 8;              // ks=0 swizzled 16B chunk
  int ko1 = ((4 + cl) ^ fx) * 8;        // ks=1

  int nt = K >> 6;  // K-tiles of 64 (>= 16 for all our shapes)

  // staging source (pre-swizzled): thread t covers row tr (+64c), chunk jx
  int tr = t >> 3;
  int jx = (t & 7) ^ (tr & 7);
  const unsigned short* pA = A + (size_t)(bm0 + tr) * K + jx * 8;
  const unsigned short* pB = Bt + (size_t)(bn0 + tr) * K + jx * 8;

  auto stA = [&](int kt2, int slot, int c) {
    gld_lds16(pA + (size_t)kt2 * 64 + (size_t)c * 64 * K, &As[slot][c * 4096 + t * 8]);
  };
  auto stB = [&](int kt2, int slot, int c) {
    gld_lds16(pB + (size_t)kt2 * 64 + (size_t)c * 64 * K, &Bs[slot][c * 4096 + t * 8]);
  };

  f32x4 acc[4][4] = {};
  bf16x8 fa[4], fb[4], ra[4], rb[4];

  // prologue: stage T0, T1 (12 loads); vmcnt(6) -> T0 landed; barrier
  stA(0, 0, 0); stA(0, 0, 1); stA(0, 0, 2); stA(0, 0, 3); stB(0, 0, 0); stB(0, 0, 1);
  stA(1, 1, 0); stA(1, 1, 1); stA(1, 1, 2); stA(1, 1, 3); stB(1, 1, 0); stB(1, 1, 1);
  asm volatile("s_waitcnt vmcnt(6)" ::: "memory");
  __builtin_amdgcn_s_barrier();
  // initial ks0 fragments of tile 0
#pragma unroll
  for (int m = 0; m < 4; ++m) fa[m] = *(const bf16x8*)&As[0][(rA0 + m * 16) * 64 + ko0];
#pragma unroll
  for (int n = 0; n < 4; ++n) fb[n] = *(const bf16x8*)&Bs[0][(rB0 + n * 16) * 64 + ko0];

  int s = 0;
  for (int kt = 0; kt < nt; ++kt) {
    const unsigned short* as = As[s];
    const unsigned short* bs = Bs[s];
    int s1 = s + 1; if (s1 == 3) s1 = 0;
    int s2 = s1 + 1; if (s2 == 3) s2 = 0;
    bool p1 = kt + 1 < nt, p2 = kt + 2 < nt;

    // stage first half of T+2; issue ks1 reads; counted wait; MFMA ks0
    if (p2) { stA(kt + 2, s2, 0); stA(kt + 2, s2, 1); stB(kt + 2, s2, 0); }
#pragma unroll
    for (int m = 0; m < 4; ++m) ra[m] = *(const bf16x8*)&as[(rA0 + m * 16) * 64 + ko1];
#pragma unroll
    for (int n = 0; n < 4; ++n) rb[n] = *(const bf16x8*)&bs[(rB0 + n * 16) * 64 + ko1];
    asm volatile("s_waitcnt lgkmcnt(8)" ::: "memory");  // fa/fb resident; ra/rb in flight
    __builtin_amdgcn_sched_barrier(0);
    __builtin_amdgcn_s_setprio(1);
#pragma unroll
    for (int m = 0; m < 4; ++m)
#pragma unroll
      for (int n = 0; n < 4; ++n)
        acc[m][n] = __builtin_amdgcn_mfma_f32_16x16x32_bf16(fa[m], fb[n], acc[m][n], 0, 0, 0);
    __builtin_amdgcn_s_setprio(0);

    // stage second half of T+2; counted vmcnt; issue T+1 ks0 reads; MFMA ks1
    if (p2) { stA(kt + 2, s2, 2); stA(kt + 2, s2, 3); stB(kt + 2, s2, 1); }
    if (p1) {
      if (p2) { asm volatile("s_waitcnt vmcnt(6)" ::: "memory"); }   // S(T+1) landed
      else    { asm volatile("s_waitcnt vmcnt(0)" ::: "memory"); }   // cheap (old loads)
      const unsigned short* as1 = As[s1];
      const unsigned short* bs1 = Bs[s1];
#pragma unroll
      for (int m = 0; m < 4; ++m) fa[m] = *(const bf16x8*)&as1[(rA0 + m * 16) * 64 + ko0];
#pragma unroll
      for (int n = 0; n < 4; ++n) fb[n] = *(const bf16x8*)&bs1[(rB0 + n * 16) * 64 + ko0];
      asm volatile("s_waitcnt lgkmcnt(8)" ::: "memory");  // ra/rb resident; fa/fb in flight
    } else {
      asm volatile("s_waitcnt lgkmcnt(0)" ::: "memory");  // last tile: ra/rb resident
    }
    __builtin_amdgcn_sched_barrier(0);
    __builtin_amdgcn_s_setprio(1);
#pragma unroll
    for (int m = 0; m < 4; ++m)
#pragma unroll
      for (int n = 0; n < 4; ++n)
        acc[m][n] = __builtin_amdgcn_mfma_f32_16x16x32_bf16(ra[m], rb[n], acc[m][n], 0, 0, 0);
    __builtin_amdgcn_s_setprio(0);
    if (p1) __builtin_amdgcn_s_barrier();  // slot protection (one barrier per tile)
    s = s1;
  }

  // epilogue (16x16 C layout: col=lane&15, row=(lane>>4)*4+reg)
#pragma unroll
  for (int m = 0; m < 4; ++m) {
#pragma unroll
    for (int n = 0; n < 4; ++n) {
#pragma unroll
      for (int r = 0; r < 4; ++r) {
        int row = bm0 + wr * 64 + m * 16 + cl * 4 + r;
        int col = bn0 + wc * 64 + n * 16 + frr;
        size_t o = (size_t)row * N + col;
        float v = acc[m][n][r] + bias[col];
        if (SILU) v = v / (1.0f + __expf(-v));
        if (GATE) v = bf2f(gate[o]) * v + bf2f(xresb[o]);
        if (RESBF) v += bf2f(resb[o]);
        if (OUT_BF16)
          ((unsigned short*)Cv)[o] = f2bf(v);
        else
          ((float*)Cv)[o] = v;
      }
    }
  }
}

// ---------------------------------------------------------------------------
extern "C" void kernel_launch(void* const* d_in, const int* in_sizes, int n_in,
                              void* d_out, int out_size, void* d_ws, size_t ws_size,
                              hipStream_t stream) {
  const float* x      = (const float*)d_in[0];
  const float* ln_g   = (const float*)d_in[1];
  const float* ln_b   = (const float*)d_in[2];
  const float* fc_w   = (const float*)d_in[3];
  const float* fc_b   = (const float*)d_in[4];
  const float* w1     = (const float*)d_in[5];
  const float* b1     = (const float*)d_in[6];
  const float* w2     = (const float*)d_in[7];
  const float* b2     = (const float*)d_in[8];
  const float* ph_re  = (const float*)d_in[9];
  const float* ph_im  = (const float*)d_in[10];
  const float* phi_re = (const float*)d_in[11];
  const float* phi_im = (const float*)d_in[12];
  const float* lci_re = (const float*)d_in[13];
  const float* lci_im = (const float*)d_in[14];
  float* out = (float*)d_out;

  char* ws = (char*)d_ws;
  const size_t SZ_BF = (size_t)ROWS * D_ * 2;  // 33,554,432 bytes
  unsigned short* xn_x2 = (unsigned short*)(ws);               // xn; after conv: x2 (bf16)
  unsigned short* cbuf  = (unsigned short*)(ws + SZ_BF);       // conv output
  unsigned short* xb_x3 = (unsigned short*)(ws + 2 * SZ_BF);   // x bf16; after gemm1: x3
  unsigned short* h1    = (unsigned short*)(ws + 3 * SZ_BF);   // [ROWS, FF] bf16 (2*SZ_BF)
  unsigned short* fc_wt = (unsigned short*)(ws + 5 * SZ_BF);
  unsigned short* w1t   = (unsigned short*)(ws + 5 * SZ_BF + (size_t)D_ * D_ * 2);
  unsigned short* w2t   = (unsigned short*)(ws + 5 * SZ_BF + (size_t)D_ * D_ * 2 + (size_t)D_ * FF_ * 2);
  float2* rloc  = (float2*)(ws + 5 * SZ_BF + (size_t)D_ * D_ * 2 + 2 * (size_t)D_ * FF_ * 2);
  float2* carry = rloc + (size_t)B_ * CG * D_;

  // weight prep (bf16, transposed to [N,K])
  transpose_cast<<<dim3(D_ / 32, D_ / 32), 256, 0, stream>>>(fc_w, fc_wt, D_, D_);
  transpose_cast<<<dim3(FF_ / 32, D_ / 32), 256, 0, stream>>>(w1, w1t, D_, FF_);
  transpose_cast<<<dim3(D_ / 32, FF_ / 32), 256, 0, stream>>>(w2, w2t, FF_, D_);

  // LN1 + cast
  ln1_kernel<<<ROWS, 256, 0, stream>>>(x, ln_g, ln_b, xn_x2, xb_x3);

  // conv (chunked scan)
  conv_pass1<<<dim3(D_ / 256, CG, B_), 256, 0, stream>>>(xn_x2, ph_re, ph_im, rloc);
  conv_pass2<<<dim3((B_ * D_) / 256), 256, 0, stream>>>(ph_re, ph_im, rloc, carry);
  conv_pass3<<<dim3(D_ / 256, CG, B_), 256, 0, stream>>>(xn_x2, ph_re, ph_im, phi_re, phi_im,
                                                         lci_re, lci_im, carry, cbuf);

  // x2 = c * silu(x @ fc_w + fc_b) + x   (bf16 -> xn region, now free)
  gemm_bt<1, 0, 1, 1><<<(ROWS / 256) * (D_ / 128), 512, 0, stream>>>(
      xb_x3, fc_wt, fc_b, nullptr, cbuf, xb_x3, xn_x2, D_ / 128, 4, D_, D_);

  // x3 = LN(x2) (bf16, into xb region)
  ln2b_kernel<<<ROWS, 256, 0, stream>>>(xn_x2, ln_g, ln_b, xb_x3);

  // h1 = silu(x3 @ w1 + b1)
  gemm_bt<1, 0, 1, 0><<<(ROWS / 256) * (FF_ / 128), 512, 0, stream>>>(
      xb_x3, w1t, b1, nullptr, nullptr, nullptr, h1, FF_ / 128, 4, FF_, D_);

  // out = x2 + h1 @ w2 + b2   (f32 out; residual read bf16)
  gemm_bt<0, 1, 0, 0><<<(ROWS / 256) * (D_ / 128), 512, 0, stream>>>(
      h1, w2t, b2, xn_x2, nullptr, nullptr, out, D_ / 128, 2, D_, FF_);
}

// Round 12
// 261.580 us; speedup vs baseline: 1.3381x; 1.3381x over previous
//
#include <hip/hip_runtime.h>
#include <hip/hip_bf16.h>
#include <hip/hip_fp8.h>
#include <cstdint>
#include <cstddef>

#define B_ 4
#define L_ 4096
#define D_ 1024
#define FF_ 2048
#define ROWS (B_ * L_)   // 16384
#define EPS_ 1e-5f
#define CG 64            // conv chunks
#define CC 64            // conv chunk length (L_/CG)

typedef __attribute__((ext_vector_type(8))) __bf16 bf16x8;
typedef __attribute__((ext_vector_type(4))) float f32x4;
typedef __attribute__((ext_vector_type(4))) unsigned short us4;

__device__ __forceinline__ float bf2f(unsigned short u) {
  union { unsigned int i; float f; } v; v.i = ((unsigned int)u) << 16; return v.f;
}
__device__ __forceinline__ unsigned short f2bf(float f) {
  union { float f; unsigned int i; } v; v.f = f;
  unsigned int r = v.i + 0x7fffu + ((v.i >> 16) & 1u);
  return (unsigned short)(r >> 16);
}
__device__ __forceinline__ unsigned char f2fp8(float f) {
  __hip_fp8_e4m3 q(f);
  return *reinterpret_cast<unsigned char*>(&q);
}

// ---------------- weight transpose + cast: in [K,N] f32 -> out [N,K] bf16 ----
__global__ __launch_bounds__(256) void transpose_cast(
    const float* __restrict__ in, unsigned short* __restrict__ out, int K, int N) {
  __shared__ float tb[32][33];
  int n0 = blockIdx.x * 32, k0 = blockIdx.y * 32;
  int tx = threadIdx.x & 31, ty = threadIdx.x >> 5;  // 32 x 8
#pragma unroll
  for (int i = 0; i < 4; ++i) {
    int k = ty + i * 8;
    tb[k][tx] = in[(size_t)(k0 + k) * N + n0 + tx];
  }
  __syncthreads();
#pragma unroll
  for (int i = 0; i < 4; ++i) {
    int n = ty + i * 8;
    out[(size_t)(n0 + n) * K + k0 + tx] = f2bf(tb[tx][n]);
  }
}

// ---------------- weight transpose + cast fp8: [K,N] f32 -> [N,K] e4m3*scale -
__global__ __launch_bounds__(256) void transpose_cast_fp8(
    const float* __restrict__ in, unsigned char* __restrict__ out, int K, int N,
    float scale) {
  __shared__ float tb[32][33];
  int n0 = blockIdx.x * 32, k0 = blockIdx.y * 32;
  int tx = threadIdx.x & 31, ty = threadIdx.x >> 5;
#pragma unroll
  for (int i = 0; i < 4; ++i) {
    int k = ty + i * 8;
    tb[k][tx] = in[(size_t)(k0 + k) * N + n0 + tx];
  }
  __syncthreads();
#pragma unroll
  for (int i = 0; i < 4; ++i) {
    int n = ty + i * 8;
    out[(size_t)(n0 + n) * K + k0 + tx] = f2fp8(tb[tx][n] * scale);
  }
}

// ---------------- LN1: x -> xn bf16 (LayerNorm), xb bf16 (plain cast) --------
__global__ __launch_bounds__(256) void ln1_kernel(
    const float* __restrict__ x, const float* __restrict__ g, const float* __restrict__ b,
    unsigned short* __restrict__ xn, unsigned short* __restrict__ xb) {
  int row = blockIdx.x;
  int t = threadIdx.x;
  const float4* xr = (const float4*)(x + (size_t)row * D_);
  float4 v = xr[t];
  float s = v.x + v.y + v.z + v.w;
  float sq = v.x * v.x + v.y * v.y + v.z * v.z + v.w * v.w;
#pragma unroll
  for (int off = 32; off > 0; off >>= 1) {
    s += __shfl_down(s, off);
    sq += __shfl_down(sq, off);
  }
  __shared__ float ls[4], lq[4];
  int lane = t & 63, w = t >> 6;
  if (lane == 0) { ls[w] = s; lq[w] = sq; }
  __syncthreads();
  s = ls[0] + ls[1] + ls[2] + ls[3];
  sq = lq[0] + lq[1] + lq[2] + lq[3];
  float mean = s * (1.0f / D_);
  float var = sq * (1.0f / D_) - mean * mean;
  float rstd = rsqrtf(var + EPS_);
  float4 gv = ((const float4*)g)[t];
  float4 bv = ((const float4*)b)[t];
  us4 o, ob;
  o.x = f2bf((v.x - mean) * rstd * gv.x + bv.x);
  o.y = f2bf((v.y - mean) * rstd * gv.y + bv.y);
  o.z = f2bf((v.z - mean) * rstd * gv.z + bv.z);
  o.w = f2bf((v.w - mean) * rstd * gv.w + bv.w);
  ob.x = f2bf(v.x); ob.y = f2bf(v.y); ob.z = f2bf(v.z); ob.w = f2bf(v.w);
  ((us4*)(xn + (size_t)row * D_))[t] = o;
  ((us4*)(xb + (size_t)row * D_))[t] = ob;
}

// ---------------- conv pass 1: per-chunk local recurrence --------------------
__global__ __launch_bounds__(256) void conv_pass1(
    const unsigned short* __restrict__ xn, const float* __restrict__ ph_re,
    const float* __restrict__ ph_im, float2* __restrict__ rloc) {
  int d = blockIdx.x * 256 + threadIdx.x;
  int g = blockIdx.y, b = blockIdx.z;
  float re = ph_re[d], im = ph_im[d];
  float a = sqrtf(re * re + im * im);
  float sc = expf(-a) / a;
  float pr = re * sc, pi = im * sc;
  float rr = 0.f, ri = 0.f;
  const unsigned short* xp = xn + ((size_t)(b * L_ + g * CC)) * D_ + d;
#pragma unroll 8
  for (int l = 0; l < CC; ++l) {
    float xv = bf2f(xp[(size_t)l * D_]);
    float nr = pr * rr - pi * ri + xv;
    ri = pr * ri + pi * rr;
    rr = nr;
  }
  rloc[((size_t)(b * CG + g)) * D_ + d] = make_float2(rr, ri);
}

// ---------------- conv pass 2: scan over chunks (batch-8 prefetched) ---------
__global__ __launch_bounds__(256) void conv_pass2(
    const float* __restrict__ ph_re, const float* __restrict__ ph_im,
    const float2* __restrict__ rloc, float2* __restrict__ carry) {
  int idx = blockIdx.x * 256 + threadIdx.x;  // 0..B*D-1
  int b = idx >> 10, d = idx & (D_ - 1);
  float re = ph_re[d], im = ph_im[d];
  float a = sqrtf(re * re + im * im);
  float th = atan2f(im, re);
  float rho = expf(-a * (float)CC);
  float ang = th * (float)CC;
  float pcr = rho * cosf(ang), pci = rho * sinf(ang);
  float cr = 0.f, ci = 0.f;
  for (int g0 = 0; g0 < CG; g0 += 8) {
    float2 rl[8];
    float2 cw[8];
#pragma unroll
    for (int i = 0; i < 8; ++i)
      rl[i] = rloc[((size_t)(b * CG + g0 + i)) * D_ + d];
#pragma unroll
    for (int i = 0; i < 8; ++i) {
      cw[i] = make_float2(cr, ci);
      float nr = pcr * cr - pci * ci + rl[i].x;
      ci = pcr * ci + pci * cr + rl[i].y;
      cr = nr;
    }
#pragma unroll
    for (int i = 0; i < 8; ++i)
      carry[((size_t)(b * CG + g0 + i)) * D_ + d] = cw[i];
  }
}

// ---------------- conv pass 3: outputs -------------------------------------
__global__ __launch_bounds__(256) void conv_pass3(
    const unsigned short* __restrict__ xn,
    const float* __restrict__ ph_re, const float* __restrict__ ph_im,
    const float* __restrict__ phi_re, const float* __restrict__ phi_im,
    const float* __restrict__ lci_re, const float* __restrict__ lci_im,
    const float2* __restrict__ carry, unsigned short* __restrict__ cout) {
  int d = blockIdx.x * 256 + threadIdx.x;
  int g = blockIdx.y, b = blockIdx.z;
  float re = ph_re[d], im = ph_im[d];
  float a = sqrtf(re * re + im * im);
  float sc = expf(-a) / a;
  float pr = re * sc, pi = im * sc;
  float th = atan2f(im, re);
  int l0 = g * CC;
  float rho = expf(-a * (float)(l0 + 1));
  float ang = th * (float)(l0 + 1);
  float prr = rho * cosf(ang), pri = rho * sinf(ang);
  float fr = phi_re[d], fi = phi_im[d];
  float qr = lci_re[d], qi = lci_im[d];
  float2 cv = carry[((size_t)(b * CG + g)) * D_ + d];
  float rr = cv.x, ri = cv.y;
  const unsigned short* xp = xn + ((size_t)(b * L_ + l0)) * D_ + d;
  unsigned short* cp = cout + ((size_t)(b * L_ + l0)) * D_ + d;
#pragma unroll 4
  for (int l = 0; l < CC; ++l) {
    float xv = bf2f(xp[(size_t)l * D_]);
    float nr = pr * rr - pi * ri + xv;
    ri = pr * ri + pi * rr;
    rr = nr;
    float outv = fr * rr - fi * ri + qr * prr - qi * pri;  // Re(phi*r + lci*p)
    cp[(size_t)l * D_] = f2bf(outv);
    float pn = pr * prr - pi * pri;
    pri = pr * pri + pi * prr;
    prr = pn;
  }
}

// ---------------- LN2c: x3 = LN(x2 bf16) -> fp8 e4m3 ------------------------
__global__ __launch_bounds__(256) void ln2c_kernel(
    const unsigned short* __restrict__ x2, const float* __restrict__ g,
    const float* __restrict__ b, unsigned char* __restrict__ x3) {
  int row = blockIdx.x;
  int t = threadIdx.x;
  size_t base = (size_t)row * D_;
  us4 vb = ((const us4*)(x2 + base))[t];
  float4 v;
  v.x = bf2f(vb.x); v.y = bf2f(vb.y); v.z = bf2f(vb.z); v.w = bf2f(vb.w);
  float s = v.x + v.y + v.z + v.w;
  float sq = v.x * v.x + v.y * v.y + v.z * v.z + v.w * v.w;
#pragma unroll
  for (int off = 32; off > 0; off >>= 1) {
    s += __shfl_down(s, off);
    sq += __shfl_down(sq, off);
  }
  __shared__ float ls[4], lq[4];
  int lane = t & 63, w = t >> 6;
  if (lane == 0) { ls[w] = s; lq[w] = sq; }
  __syncthreads();
  s = ls[0] + ls[1] + ls[2] + ls[3];
  sq = lq[0] + lq[1] + lq[2] + lq[3];
  float mean = s * (1.0f / D_);
  float var = sq * (1.0f / D_) - mean * mean;
  float rstd = rsqrtf(var + EPS_);
  float4 gv = ((const float4*)g)[t];
  float4 bv = ((const float4*)b)[t];
  uchar4 o;
  o.x = f2fp8((v.x - mean) * rstd * gv.x + bv.x);
  o.y = f2fp8((v.y - mean) * rstd * gv.y + bv.y);
  o.z = f2fp8((v.z - mean) * rstd * gv.z + bv.z);
  o.w = f2fp8((v.w - mean) * rstd * gv.w + bv.w);
  ((uchar4*)(x3 + base))[t] = o;
}

// ============================================================================
__device__ __forceinline__ void gld_lds16(const void* gp, void* lp) {
  __builtin_amdgcn_global_load_lds(
      (const __attribute__((address_space(1))) unsigned int*)gp,
      (__attribute__((address_space(3))) unsigned int*)lp, 16, 0, 0);
}

#define PHASE_SYNC()                                         \
  __builtin_amdgcn_s_barrier();                              \
  asm volatile("s_waitcnt lgkmcnt(0)" ::: "memory");         \
  __builtin_amdgcn_sched_barrier(0);                         \
  __builtin_amdgcn_s_setprio(1);

#define PHASE_END()                                          \
  __builtin_amdgcn_s_setprio(0);

// ---------------- bf16 GEMM (R10 structure, proven best) --------------------
// BM=256, BN=128, BK=64, 8 waves (4Mx2N), ring-3 144KiB, 2 phases/tile,
// vmcnt(6) counted distance-2. Used for gemm1 (gate+residual fused).
template <int SILU, int OUT_BF16, int GATE>
__global__ __launch_bounds__(512) void gemm_bt(
    const unsigned short* __restrict__ A, const unsigned short* __restrict__ Bt,
    const float* __restrict__ bias,
    const unsigned short* __restrict__ gate, const unsigned short* __restrict__ xresb,
    void* __restrict__ Cv, int NB, int GROUP, int N, int K) {
  __shared__ unsigned short As[3][256 * 64];
  __shared__ unsigned short Bs[3][128 * 64];

  int nwg = gridDim.x;
  int xcd = blockIdx.x & 7;
  int lo = blockIdx.x >> 3;
  int q = nwg >> 3;
  int gsz = GROUP * NB;
  int g_ = lo / gsz, r_ = lo % gsz;
  int n_ = r_ / GROUP, ml = r_ - n_ * GROUP;
  int Mx = q / NB;
  int bm0 = (xcd * Mx + g_ * GROUP + ml) * 256;
  int bn0 = n_ * 128;

  int t = threadIdx.x;
  int lane = t & 63, w = t >> 6;
  int wr = w >> 1, wc = w & 1;
  int frr = lane & 15, cl = lane >> 4;
  int fx = frr & 7;
  int rA0 = wr * 64 + frr;
  int rB0 = wc * 64 + frr;
  int ko0 = (cl ^ fx) * 8;
  int ko1 = ((4 + cl) ^ fx) * 8;

  int nt = K >> 6;

  int tr = t >> 3;
  int jx = (t & 7) ^ (tr & 7);
  const unsigned short* pA = A + (size_t)(bm0 + tr) * K + jx * 8;
  const unsigned short* pB = Bt + (size_t)(bn0 + tr) * K + jx * 8;

  auto stA = [&](int kt2, int slot, int c) {
    gld_lds16(pA + (size_t)kt2 * 64 + (size_t)c * 64 * K, &As[slot][c * 4096 + t * 8]);
  };
  auto stB = [&](int kt2, int slot, int c) {
    gld_lds16(pB + (size_t)kt2 * 64 + (size_t)c * 64 * K, &Bs[slot][c * 4096 + t * 8]);
  };

  f32x4 acc[4][4] = {};

  stA(0, 0, 0); stA(0, 0, 1); stA(0, 0, 2); stA(0, 0, 3); stB(0, 0, 0); stB(0, 0, 1);
  stA(1, 1, 0); stA(1, 1, 1); stA(1, 1, 2); stA(1, 1, 3); stB(1, 1, 0); stB(1, 1, 1);
  asm volatile("s_waitcnt vmcnt(6)" ::: "memory");
  __builtin_amdgcn_s_barrier();

  int s = 0;
  for (int kt = 0; kt < nt; ++kt) {
    const unsigned short* as = As[s];
    const unsigned short* bs = Bs[s];
    int s2 = s + 2; if (s2 >= 3) s2 -= 3;
    bool p2 = kt + 2 < nt;

    bf16x8 a0[4], b0[4];
#pragma unroll
    for (int m = 0; m < 4; ++m) a0[m] = *(const bf16x8*)&as[(rA0 + m * 16) * 64 + ko0];
#pragma unroll
    for (int n = 0; n < 4; ++n) b0[n] = *(const bf16x8*)&bs[(rB0 + n * 16) * 64 + ko0];
    if (p2) { stA(kt + 2, s2, 0); stA(kt + 2, s2, 1); stB(kt + 2, s2, 0); }
    PHASE_SYNC();
#pragma unroll
    for (int m = 0; m < 4; ++m)
#pragma unroll
      for (int n = 0; n < 4; ++n)
        acc[m][n] = __builtin_amdgcn_mfma_f32_16x16x32_bf16(a0[m], b0[n], acc[m][n], 0, 0, 0);
    PHASE_END();
    __builtin_amdgcn_s_barrier();

    bf16x8 a1[4], b1[4];
#pragma unroll
    for (int m = 0; m < 4; ++m) a1[m] = *(const bf16x8*)&as[(rA0 + m * 16) * 64 + ko1];
#pragma unroll
    for (int n = 0; n < 4; ++n) b1[n] = *(const bf16x8*)&bs[(rB0 + n * 16) * 64 + ko1];
    if (p2) { stA(kt + 2, s2, 2); stA(kt + 2, s2, 3); stB(kt + 2, s2, 1); }
    PHASE_SYNC();
#pragma unroll
    for (int m = 0; m < 4; ++m)
#pragma unroll
      for (int n = 0; n < 4; ++n)
        acc[m][n] = __builtin_amdgcn_mfma_f32_16x16x32_bf16(a1[m], b1[n], acc[m][n], 0, 0, 0);
    PHASE_END();
    if (p2) { asm volatile("s_waitcnt vmcnt(6)" ::: "memory"); }
    else    { asm volatile("s_waitcnt vmcnt(0)" ::: "memory"); }
    __builtin_amdgcn_s_barrier();
    s += 1; if (s == 3) s = 0;
  }

#pragma unroll
  for (int m = 0; m < 4; ++m) {
#pragma unroll
    for (int n = 0; n < 4; ++n) {
#pragma unroll
      for (int r = 0; r < 4; ++r) {
        int row = bm0 + wr * 64 + m * 16 + cl * 4 + r;
        int col = bn0 + wc * 64 + n * 16 + frr;
        size_t o = (size_t)row * N + col;
        float v = acc[m][n][r] + bias[col];
        if (SILU) v = v / (1.0f + __expf(-v));
        if (GATE) v = bf2f(gate[o]) * v + bf2f(xresb[o]);
        if (OUT_BF16)
          ((unsigned short*)Cv)[o] = f2bf(v);
        else
          ((float*)Cv)[o] = v;
      }
    }
  }
}

// ---------------- fp8 GEMM: A[M,K] e4m3 @ Bt[N,K] e4m3 -> C -----------------
// Same R10 schedule; fragments 8B (ds_read_b64), LDS ring-3 = 72 KiB ->
// 2 blocks/CU (launch_bounds(512,4)). Stage 3 gld_lds/tile, vmcnt(3) counted.
// Swizzle at 16B gld_lds atomicity: c16 ^= (row>>1)&3 -> exact 2-way (free).
// OUT: 0 = f32 (+bf16 residual), 1 = fp8 (for h1). oscale un-does weight x32.
template <int SILU, int RESBF, int OUT_FP8>
__global__ __launch_bounds__(512, 4) void gemm_f8(
    const unsigned char* __restrict__ A, const unsigned char* __restrict__ Bt,
    const float* __restrict__ bias, const unsigned short* __restrict__ resb,
    float oscale, void* __restrict__ Cv, int NB, int GROUP, int N, int K) {
  __shared__ unsigned char As[3][256 * 64];  // 3 x 16 KiB
  __shared__ unsigned char Bs[3][128 * 64];  // 3 x 8 KiB

  int nwg = gridDim.x;
  int xcd = blockIdx.x & 7;
  int lo = blockIdx.x >> 3;
  int q = nwg >> 3;
  int gsz = GROUP * NB;
  int g_ = lo / gsz, r_ = lo % gsz;
  int n_ = r_ / GROUP, ml = r_ - n_ * GROUP;
  int Mx = q / NB;
  int bm0 = (xcd * Mx + g_ * GROUP + ml) * 256;
  int bn0 = n_ * 128;

  int t = threadIdx.x;
  int lane = t & 63, w = t >> 6;
  int wr = w >> 1, wc = w & 1;          // 4M x 2N
  int frr = lane & 15, cl = lane >> 4;  // row, k-chunk (0..3)
  int sw = (frr >> 1) & 3;              // fp8 swizzle key
  int rA0 = wr * 64 + frr;
  int rB0 = wc * 64 + frr;
  // ks0: logical c16 = cl>>1; ks1: 2 + (cl>>1); sub-8B = cl&1
  int ko0 = ((((cl >> 1) ^ sw) << 4) | ((cl & 1) << 3));
  int ko1 = (((((cl >> 1) + 2) ^ sw) << 4) | ((cl & 1) << 3));

  int nt = K >> 6;  // K-tiles of 64 fp8

  // staging: per call 128 rows; thread t -> row t>>2, physical 16B chunk t&3
  int tr = t >> 2;                      // 0..127
  int jc = (t & 3) ^ ((tr >> 1) & 3);   // logical 16B chunk to fetch
  const unsigned char* pA = A + (size_t)(bm0 + tr) * K + jc * 16;
  const unsigned char* pB = Bt + (size_t)(bn0 + tr) * K + jc * 16;

  auto stA = [&](int kt2, int slot, int c) {  // c=0: rows 0-127, c=1: 128-255
    gld_lds16(pA + (size_t)kt2 * 64 + (size_t)c * 128 * K, &As[slot][c * 8192 + t * 16]);
  };
  auto stB = [&](int kt2, int slot) {
    gld_lds16(pB + (size_t)kt2 * 64, &Bs[slot][t * 16]);
  };

  f32x4 acc[4][4] = {};

  // prologue: stage T0 (3), T1 (3); vmcnt(3) -> T0 landed
  stA(0, 0, 0); stA(0, 0, 1); stB(0, 0);
  stA(1, 1, 0); stA(1, 1, 1); stB(1, 1);
  asm volatile("s_waitcnt vmcnt(3)" ::: "memory");
  __builtin_amdgcn_s_barrier();

  int s = 0;
  for (int kt = 0; kt < nt; ++kt) {
    const unsigned char* as = As[s];
    const unsigned char* bs = Bs[s];
    int s2 = s + 2; if (s2 >= 3) s2 -= 3;
    bool p2 = kt + 2 < nt;

    // phase 0 (ks=0): 8 ds_read_b64; stage A(T+2)
    long a0[4], b0[4];
#pragma unroll
    for (int m = 0; m < 4; ++m) a0[m] = *(const long*)&as[(rA0 + m * 16) * 64 + ko0];
#pragma unroll
    for (int n = 0; n < 4; ++n) b0[n] = *(const long*)&bs[(rB0 + n * 16) * 64 + ko0];
    if (p2) { stA(kt + 2, s2, 0); stA(kt + 2, s2, 1); }
    PHASE_SYNC();
#pragma unroll
    for (int m = 0; m < 4; ++m)
#pragma unroll
      for (int n = 0; n < 4; ++n)
        acc[m][n] = __builtin_amdgcn_mfma_f32_16x16x32_fp8_fp8(a0[m], b0[n], acc[m][n], 0, 0, 0);
    PHASE_END();
    __builtin_amdgcn_s_barrier();

    // phase 1 (ks=1): 8 ds_read_b64; stage B(T+2); counted vmcnt
    long a1[4], b1[4];
#pragma unroll
    for (int m = 0; m < 4; ++m) a1[m] = *(const long*)&as[(rA0 + m * 16) * 64 + ko1];
#pragma unroll
    for (int n = 0; n < 4; ++n) b1[n] = *(const long*)&bs[(rB0 + n * 16) * 64 + ko1];
    if (p2) stB(kt + 2, s2);
    PHASE_SYNC();
#pragma unroll
    for (int m = 0; m < 4; ++m)
#pragma unroll
      for (int n = 0; n < 4; ++n)
        acc[m][n] = __builtin_amdgcn_mfma_f32_16x16x32_fp8_fp8(a1[m], b1[n], acc[m][n], 0, 0, 0);
    PHASE_END();
    if (p2) { asm volatile("s_waitcnt vmcnt(3)" ::: "memory"); }
    else    { asm volatile("s_waitcnt vmcnt(0)" ::: "memory"); }
    __builtin_amdgcn_s_barrier();
    s += 1; if (s == 3) s = 0;
  }

  // epilogue (16x16 C layout: col=lane&15, row=(lane>>4)*4+reg)
#pragma unroll
  for (int m = 0; m < 4; ++m) {
#pragma unroll
    for (int n = 0; n < 4; ++n) {
#pragma unroll
      for (int r = 0; r < 4; ++r) {
        int row = bm0 + wr * 64 + m * 16 + cl * 4 + r;
        int col = bn0 + wc * 64 + n * 16 + frr;
        size_t o = (size_t)row * N + col;
        float v = acc[m][n][r] * oscale + bias[col];
        if (SILU) v = v / (1.0f + __expf(-v));
        if (RESBF) v += bf2f(resb[o]);
        if (OUT_FP8)
          ((unsigned char*)Cv)[o] = f2fp8(v);
        else
          ((float*)Cv)[o] = v;
      }
    }
  }
}

// ---------------------------------------------------------------------------
extern "C" void kernel_launch(void* const* d_in, const int* in_sizes, int n_in,
                              void* d_out, int out_size, void* d_ws, size_t ws_size,
                              hipStream_t stream) {
  const float* x      = (const float*)d_in[0];
  const float* ln_g   = (const float*)d_in[1];
  const float* ln_b   = (const float*)d_in[2];
  const float* fc_w   = (const float*)d_in[3];
  const float* fc_b   = (const float*)d_in[4];
  const float* w1     = (const float*)d_in[5];
  const float* b1     = (const float*)d_in[6];
  const float* w2     = (const float*)d_in[7];
  const float* b2     = (const float*)d_in[8];
  const float* ph_re  = (const float*)d_in[9];
  const float* ph_im  = (const float*)d_in[10];
  const float* phi_re = (const float*)d_in[11];
  const float* phi_im = (const float*)d_in[12];
  const float* lci_re = (const float*)d_in[13];
  const float* lci_im = (const float*)d_in[14];
  float* out = (float*)d_out;

  char* ws = (char*)d_ws;
  const size_t SZ_BF = (size_t)ROWS * D_ * 2;   // 32 MiB
  const size_t SZ_F8 = (size_t)ROWS * D_;       // 16 MiB
  unsigned short* xn_x2 = (unsigned short*)(ws);               // xn; then x2 bf16
  unsigned short* cbuf  = (unsigned short*)(ws + SZ_BF);       // conv out bf16
  unsigned short* xb    = (unsigned short*)(ws + 2 * SZ_BF);   // x bf16
  unsigned char*  x3f8  = (unsigned char*)(ws + 3 * SZ_BF);    // x3 fp8 (16 MiB)
  unsigned char*  h1f8  = (unsigned char*)(ws + 3 * SZ_BF + SZ_F8);  // h1 fp8 (32 MiB)
  char* wp = ws + 3 * SZ_BF + SZ_F8 + (size_t)ROWS * FF_;
  unsigned short* fc_wt = (unsigned short*)(wp);                       // 2 MiB
  unsigned char*  w1t8  = (unsigned char*)(wp + (size_t)D_ * D_ * 2);  // 2 MiB
  unsigned char*  w2t8  = (unsigned char*)(wp + (size_t)D_ * D_ * 2 + (size_t)D_ * FF_);
  float2* rloc  = (float2*)(wp + (size_t)D_ * D_ * 2 + 2 * (size_t)D_ * FF_);
  float2* carry = rloc + (size_t)B_ * CG * D_;

  // weight prep
  transpose_cast<<<dim3(D_ / 32, D_ / 32), 256, 0, stream>>>(fc_w, fc_wt, D_, D_);
  transpose_cast_fp8<<<dim3(FF_ / 32, D_ / 32), 256, 0, stream>>>(w1, w1t8, D_, FF_, 32.0f);
  transpose_cast_fp8<<<dim3(D_ / 32, FF_ / 32), 256, 0, stream>>>(w2, w2t8, FF_, D_, 32.0f);

  // LN1 + cast
  ln1_kernel<<<ROWS, 256, 0, stream>>>(x, ln_g, ln_b, xn_x2, xb);

  // conv (chunked scan)
  conv_pass1<<<dim3(D_ / 256, CG, B_), 256, 0, stream>>>(xn_x2, ph_re, ph_im, rloc);
  conv_pass2<<<dim3((B_ * D_) / 256), 256, 0, stream>>>(ph_re, ph_im, rloc, carry);
  conv_pass3<<<dim3(D_ / 256, CG, B_), 256, 0, stream>>>(xn_x2, ph_re, ph_im, phi_re, phi_im,
                                                         lci_re, lci_im, carry, cbuf);

  // x2 = c * silu(x @ fc_w + fc_b) + x   (bf16 -> xn region; bf16 gemm)
  gemm_bt<1, 1, 1><<<(ROWS / 256) * (D_ / 128), 512, 0, stream>>>(
      xb, fc_wt, fc_b, cbuf, xb, xn_x2, D_ / 128, 4, D_, D_);

  // x3 = LN(x2) -> fp8
  ln2c_kernel<<<ROWS, 256, 0, stream>>>(xn_x2, ln_g, ln_b, x3f8);

  // h1 = silu(x3 @ (32*w1) / 32 + b1) -> fp8   [fp8 gemm]
  gemm_f8<1, 0, 1><<<(ROWS / 256) * (FF_ / 128), 512, 0, stream>>>(
      x3f8, w1t8, b1, nullptr, 1.0f / 32.0f, h1f8, FF_ / 128, 4, FF_, D_);

  // out = x2 + h1 @ (32*w2) / 32 + b2   [fp8 gemm, f32 out]
  gemm_f8<0, 1, 0><<<(ROWS / 256) * (D_ / 128), 512, 0, stream>>>(
      h1f8, w2t8, b2, xn_x2, 1.0f / 32.0f, out, D_ / 128, 2, D_, FF_);
}